// Round 9
// baseline (947.126 us; speedup 1.0000x reference)
//
#include <hip/hip_runtime.h>
#include <hip/hip_cooperative_groups.h>
#include <math.h>

// EthicalGNN: encoder -> 3x(GAT + BN (+ReLU)) -> mean-pool -> 2 MLP heads.
// R9: cooperative mega-kernel with occupancy-sized grid + checked launch;
// full R7 multi-kernel fallback if the cooperative launch is rejected.

namespace cg = cooperative_groups;

#define H4 4
constexpr int TB = 256;

static __device__ __forceinline__ unsigned short f2bf(float f) {
  unsigned u = __float_as_uint(f);
  u += 0x7fffu + ((u >> 16) & 1u);  // round-to-nearest-even
  return (unsigned short)(u >> 16);
}
static __device__ __forceinline__ float bfh(unsigned u) { return __uint_as_float(u << 16); }
static __device__ __forceinline__ float bfl(unsigned u) { return __uint_as_float(u & 0xffff0000u); }

struct Pr {
  const float* x; const int* esrc; const int* edst;
  const float* encW; const float* encb;
  const float* W[3]; const float* as_[3]; const float* ad[3];
  const float* b[3]; const float* g[3]; const float* be[3];
  const float* m[3]; const float* v[3];
  const float* eW1; const float* eb1; const float* eW2; const float* eb2;
  const float* mW1; const float* mb1; const float* mW2; const float* mb2;
  float* hA; float* hB; unsigned short* xpb; float* als; float* ald;
  float* pas; float* pad; float* gpart;
  int* col; int* rbeg; int* rend; int* cursor; int* counter;
  float* out; int N; int E;
};

// ==================== shared device stages ====================

// xp(bf16) = hin @ W ; als/ald = hin @ was/wad. Blocks [bstart, bstart+bnum).
template <int HC, bool ENC>
__device__ void gemm_stage(const Pr& p, const float* hin, const float* W,
                           const float* was, const float* wad, float* hs,
                           int bstart, int bnum) {
  int b = (int)blockIdx.x - bstart;
  if (b < 0 || b >= bnum) return;  // whole block skips together
  int tid = threadIdx.x;
  int ntile = (p.N + 15) >> 4;
  for (int t = b; t < ntile; t += bnum) {
    int n0 = t << 4;
    for (int idx = tid; idx < 1024; idx += TB) {
      int i = idx >> 6, j = idx & 63;
      int n = n0 + i;
      float a = 0.f;
      if (ENC) {
        if (n < p.N) {
          a = p.encb[j];
#pragma unroll
          for (int k = 0; k < 5; ++k) a += p.x[n * 5 + k] * p.encW[k * 64 + j];
        }
      } else {
        a = (n < p.N) ? hin[(size_t)n * 64 + j] : 0.f;
      }
      hs[idx] = a;
    }
    __syncthreads();
    if (tid < HC) {
      float acc[16];
#pragma unroll
      for (int i = 0; i < 16; ++i) acc[i] = 0.f;
      for (int k = 0; k < 64; k += 4) {
        float w0 = W[(k + 0) * HC + tid];
        float w1 = W[(k + 1) * HC + tid];
        float w2 = W[(k + 2) * HC + tid];
        float w3 = W[(k + 3) * HC + tid];
#pragma unroll
        for (int i = 0; i < 16; ++i) {
          float4 hv = *(const float4*)&hs[i * 64 + k];
          acc[i] += hv.x * w0 + hv.y * w1 + hv.z * w2 + hv.w * w3;
        }
      }
#pragma unroll
      for (int i = 0; i < 16; ++i) {
        int n = n0 + i;
        if (n < p.N) p.xpb[(size_t)n * HC + tid] = f2bf(acc[i]);
      }
    }
    if (tid < 64) {  // logits: (node i, head h) pairs, dot from LDS
      int i = tid >> 2, h = tid & 3;
      int n = n0 + i;
      float vs = 0.f, vd = 0.f;
#pragma unroll 8
      for (int k = 0; k < 64; ++k) {
        float hv = hs[i * 64 + k];
        vs += hv * was[k * 4 + h];
        vd += hv * wad[k * 4 + h];
      }
      if (n < p.N) {
        p.als[n * H4 + h] = vs;
        p.ald[n * H4 + h] = vd;
      }
    }
    __syncthreads();
  }
}

// one wave per node, grid-stride, 4 edges in flight
template <int C, bool RELU, bool POOL>
__device__ void gather_stage(const Pr& p, float* hout, const float* bias,
                             const float* g, const float* be, const float* m,
                             const float* v) {
  constexpr int HC = H4 * C;
  constexpr int VPL = HC / 64;
  int lane = threadIdx.x & 63;
  int h = lane >> 4;
  int wid = blockIdx.x * 4 + (threadIdx.x >> 6);
  int wstride = gridDim.x * 4;
  for (int n = wid; n < p.N; n += wstride) {
    float aldn = p.ald[n * H4 + h];
    int beg = p.rbeg[n], end = p.rend[n];
    float s = 0.f;
    float acc[VPL];
#pragma unroll
    for (int i = 0; i < VPL; ++i) acc[i] = 0.f;
    int j = beg;
    for (; j + 3 < end; j += 4) {
      int s0 = p.col[j], s1 = p.col[j + 1], s2 = p.col[j + 2], s3 = p.col[j + 3];
      float a0 = p.als[s0 * H4 + h], a1 = p.als[s1 * H4 + h];
      float a2 = p.als[s2 * H4 + h], a3 = p.als[s3 * H4 + h];
      float e0 = a0 + aldn; e0 = (e0 > 0.f) ? e0 : 0.2f * e0; e0 = __expf(e0);
      float e1 = a1 + aldn; e1 = (e1 > 0.f) ? e1 : 0.2f * e1; e1 = __expf(e1);
      float e2 = a2 + aldn; e2 = (e2 > 0.f) ? e2 : 0.2f * e2; e2 = __expf(e2);
      float e3 = a3 + aldn; e3 = (e3 > 0.f) ? e3 : 0.2f * e3; e3 = __expf(e3);
      s += (e0 + e1) + (e2 + e3);
      if constexpr (VPL == 4) {
        uint2 u0 = *(const uint2*)(p.xpb + (size_t)s0 * HC + lane * 4);
        uint2 u1 = *(const uint2*)(p.xpb + (size_t)s1 * HC + lane * 4);
        uint2 u2 = *(const uint2*)(p.xpb + (size_t)s2 * HC + lane * 4);
        uint2 u3 = *(const uint2*)(p.xpb + (size_t)s3 * HC + lane * 4);
        acc[0] += e0 * bfh(u0.x) + e1 * bfh(u1.x) + e2 * bfh(u2.x) + e3 * bfh(u3.x);
        acc[1] += e0 * bfl(u0.x) + e1 * bfl(u1.x) + e2 * bfl(u2.x) + e3 * bfl(u3.x);
        acc[2] += e0 * bfh(u0.y) + e1 * bfh(u1.y) + e2 * bfh(u2.y) + e3 * bfh(u3.y);
        acc[3] += e0 * bfl(u0.y) + e1 * bfl(u1.y) + e2 * bfl(u2.y) + e3 * bfl(u3.y);
      } else {
        unsigned u0 = *(const unsigned*)(p.xpb + (size_t)s0 * HC + lane * 2);
        unsigned u1 = *(const unsigned*)(p.xpb + (size_t)s1 * HC + lane * 2);
        unsigned u2 = *(const unsigned*)(p.xpb + (size_t)s2 * HC + lane * 2);
        unsigned u3 = *(const unsigned*)(p.xpb + (size_t)s3 * HC + lane * 2);
        acc[0] += e0 * bfh(u0) + e1 * bfh(u1) + e2 * bfh(u2) + e3 * bfh(u3);
        acc[1] += e0 * bfl(u0) + e1 * bfl(u1) + e2 * bfl(u2) + e3 * bfl(u3);
      }
    }
    for (; j < end; ++j) {
      int s0 = p.col[j];
      float a0 = p.als[s0 * H4 + h];
      float e0 = a0 + aldn; e0 = (e0 > 0.f) ? e0 : 0.2f * e0; e0 = __expf(e0);
      s += e0;
      if constexpr (VPL == 4) {
        uint2 u0 = *(const uint2*)(p.xpb + (size_t)s0 * HC + lane * 4);
        acc[0] += e0 * bfh(u0.x);
        acc[1] += e0 * bfl(u0.x);
        acc[2] += e0 * bfh(u0.y);
        acc[3] += e0 * bfl(u0.y);
      } else {
        unsigned u0 = *(const unsigned*)(p.xpb + (size_t)s0 * HC + lane * 2);
        acc[0] += e0 * bfh(u0);
        acc[1] += e0 * bfl(u0);
      }
    }
    float inv = 1.f / (s + 1e-16f);
#pragma unroll
    for (int i = 0; i < VPL; ++i) {
      acc[i] *= inv;
      acc[i] += __shfl_xor(acc[i], 16, 64);
      acc[i] += __shfl_xor(acc[i], 32, 64);
    }
    if (lane < 16) {
      int c0 = lane * VPL;
      float o[VPL];
#pragma unroll
      for (int i = 0; i < VPL; ++i) {
        int cc = c0 + i;
        float t = acc[i] * (1.f / H4) + bias[cc];
        t = (t - m[cc]) * rsqrtf(v[cc] + 1e-5f) * g[cc] + be[cc];
        if (RELU) t = fmaxf(t, 0.f);
        o[i] = t;
        if (POOL) atomicAdd(&p.gpart[(n & 255) * 32 + cc], t);
      }
      if constexpr (VPL == 4)
        *(float4*)&hout[(size_t)n * C + c0] = make_float4(o[0], o[1], o[2], o[3]);
      else
        *(float2*)&hout[(size_t)n * C + c0] = make_float2(o[0], o[1]);
    }
  }
}

// ==================== cooperative mega-kernel ====================
__global__ __launch_bounds__(TB, 4) void mega(Pr p) {
  cg::grid_group grid = cg::this_grid();
  __shared__ float hs[1024];
  const int tid = threadIdx.x;
  const int lane = tid & 63;
  const int GBx = gridDim.x;
  const int gtid = blockIdx.x * TB + tid;
  const int GS = GBx * TB;

  // ---- S0: zero cursor/counter/gpart (contiguous ints); was/wad on blocks 0-2 ----
  {
    int Z = p.N + 1 + 256 * 32;
    int* zb = p.cursor;
    for (int i = gtid; i < Z; i += GS) zb[i] = 0;
    if (blockIdx.x < 3) {
      int l = blockIdx.x;
      const float* W = p.W[l];
      const float* ap = p.as_[l];
      const float* dp = p.ad[l];
      int HC = (l == 2) ? 128 : 256;
      int C = HC / H4;
      int k = tid >> 2, h = tid & 3;
      float vs = 0.f, vd = 0.f;
      for (int c = 0; c < C; ++c) {
        float w = W[k * HC + h * C + c];
        vs += w * ap[h * C + c];
        vd += w * dp[h * C + c];
      }
      p.pas[l * 256 + tid] = vs;
      p.pad[l * 256 + tid] = vd;
    }
  }
  grid.sync();

  // ---- S1: edge count (first quarter) || layer-0 GEMM (rest) ----
  {
    int cnt = GBx >> 2;
    if ((int)blockIdx.x < cnt) {
      for (int i = blockIdx.x * TB + tid; i < p.E; i += cnt * TB)
        atomicAdd(&p.cursor[p.edst[i]], 1);
    } else {
      gemm_stage<256, true>(p, p.x, p.W[0], p.pas, p.pad, hs, cnt, GBx - cnt);
    }
  }
  grid.sync();

  // ---- S2: region alloc (wave shfl-scan + one atomicAdd per wave) ----
  for (int base = blockIdx.x * TB + (tid & ~63); base < p.N; base += GS) {
    int gid = base + lane;
    int dval = (gid < p.N) ? atomicAdd(&p.cursor[gid], 0) : -1;  // coherent read
    int size = (gid < p.N) ? dval + 1 : 0;  // +1 self-loop
    int v = size;
#pragma unroll
    for (int off = 1; off < 64; off <<= 1) {
      int t = __shfl_up(v, off, 64);
      if (lane >= off) v += t;
    }
    int tot = __shfl(v, 63, 64);
    int b0 = 0;
    if (lane == 63) b0 = atomicAdd(p.counter, tot);
    b0 = __shfl(b0, 63, 64);
    if (gid < p.N) {
      int pos = b0 + v - size;
      p.rbeg[gid] = pos;
      p.rend[gid] = pos + size;
      p.col[pos] = gid;  // self-loop
      p.cursor[gid] = pos + 1;
    }
  }
  grid.sync();

  // ---- S3: scatter edges ----
  for (int i = gtid; i < p.E; i += GS) {
    int pos = atomicAdd(&p.cursor[p.edst[i]], 1);
    p.col[pos] = p.esrc[i];
  }
  grid.sync();

  gather_stage<64, true, false>(p, p.hB, p.b[0], p.g[0], p.be[0], p.m[0], p.v[0]);
  grid.sync();
  gemm_stage<256, false>(p, p.hB, p.W[1], p.pas + 256, p.pad + 256, hs, 0, GBx);
  grid.sync();
  gather_stage<64, true, false>(p, p.hA, p.b[1], p.g[1], p.be[1], p.m[1], p.v[1]);
  grid.sync();
  gemm_stage<128, false>(p, p.hA, p.W[2], p.pas + 512, p.pad + 512, hs, 0, GBx);
  grid.sync();
  gather_stage<32, false, true>(p, p.out, p.b[2], p.g[2], p.be[2], p.m[2], p.v[2]);
  grid.sync();

  // ---- heads (block 0) ----
  if (blockIdx.x == 0) {
    float* red = hs;
    float* z = hs + 256;
    float* hid = hs + 288;
    int c = tid & 31;
    float sAcc = 0.f;
    for (int bkt = tid >> 5; bkt < 256; bkt += 8)
      sAcc += atomicAdd(&p.gpart[bkt * 32 + c], 0.f);  // coherent read
    red[tid] = sAcc;
    __syncthreads();
    size_t base = (size_t)p.N * 32;
    if (tid < 32) {
      float t = 0.f;
#pragma unroll
      for (int i = 0; i < 8; ++i) t += red[i * 32 + tid];
      t /= (float)p.N;
      z[tid] = t;
      p.out[base + tid] = t;
    }
    __syncthreads();
    if (tid < 16) {
      float a = p.eb1[tid], b = p.mb1[tid];
      for (int k = 0; k < 32; ++k) {
        a += z[k] * p.eW1[k * 16 + tid];
        b += z[k] * p.mW1[k * 16 + tid];
      }
      hid[tid] = fmaxf(a, 0.f);
      hid[16 + tid] = fmaxf(b, 0.f);
    }
    __syncthreads();
    if (tid == 0) {
      float a = p.eb2[0];
      for (int k = 0; k < 16; ++k) a += hid[k] * p.eW2[k];
      p.out[base + 32] = 1.f / (1.f + __expf(-a));
    } else if (tid == 1) {
      float a = p.mb2[0];
      for (int k = 0; k < 16; ++k) a += hid[16 + k] * p.mW2[k];
      p.out[base + 33] = 1.f / (1.f + __expf(-a));
    }
  }
}

// ==================== R7 fallback kernels ====================
__global__ void k_count(const int* __restrict__ dst, int* __restrict__ deg, int E) {
  int gid = blockIdx.x * blockDim.x + threadIdx.x;
  if (gid < E) atomicAdd(&deg[dst[gid]], 1);
}

__global__ void k_alloc(Pr p) {
  int gid = blockIdx.x * blockDim.x + threadIdx.x;
  int lane = threadIdx.x & 63;
  int size = (gid < p.N) ? (p.cursor[gid] + 1) : 0;
  int v = size;
#pragma unroll
  for (int off = 1; off < 64; off <<= 1) {
    int t = __shfl_up(v, off, 64);
    if (lane >= off) v += t;
  }
  int tot = __shfl(v, 63, 64);
  int b0 = 0;
  if (lane == 63) b0 = atomicAdd(p.counter, tot);
  b0 = __shfl(b0, 63, 64);
  if (gid < p.N) {
    int pos = b0 + v - size;
    p.rbeg[gid] = pos;
    p.rend[gid] = pos + size;
    p.col[pos] = gid;
    p.cursor[gid] = pos + 1;
  }
  if (blockIdx.x < 3) {
    int l = blockIdx.x;
    const float* W = p.W[l];
    const float* ap = p.as_[l];
    const float* dp = p.ad[l];
    int HC = (l == 2) ? 128 : 256;
    int C = HC / H4;
    int tid = threadIdx.x;
    int k = tid >> 2, h = tid & 3;
    float vs = 0.f, vd = 0.f;
    for (int c = 0; c < C; ++c) {
      float w = W[k * HC + h * C + c];
      vs += w * ap[h * C + c];
      vd += w * dp[h * C + c];
    }
    p.pas[l * 256 + tid] = vs;
    p.pad[l * 256 + tid] = vd;
  }
}

__global__ void k_scatter(const int* __restrict__ src, const int* __restrict__ dst,
                          int* __restrict__ cursor, int* __restrict__ col, int E) {
  int gid = blockIdx.x * blockDim.x + threadIdx.x;
  if (gid < E) {
    int p = atomicAdd(&cursor[dst[gid]], 1);
    col[p] = src[gid];
  }
}

template <int HC, bool ENC>
__global__ void k_gemm_al(Pr p, const float* __restrict__ hin, const float* __restrict__ W,
                          const float* __restrict__ was, const float* __restrict__ wad) {
  __shared__ float hs[1024];
  gemm_stage<HC, ENC>(p, hin, W, was, wad, hs, 0, gridDim.x);
}

template <int C, bool RELU, bool POOL>
__global__ __launch_bounds__(256) void k_gather(Pr p, float* hout,
                                                const float* __restrict__ bias,
                                                const float* __restrict__ g,
                                                const float* __restrict__ be,
                                                const float* __restrict__ m,
                                                const float* __restrict__ v) {
  gather_stage<C, RELU, POOL>(p, hout, bias, g, be, m, v);
}

__global__ void k_heads2(Pr p) {
  __shared__ float red[256];
  __shared__ float z[32];
  __shared__ float hid[32];
  int tid = threadIdx.x;
  int c = tid & 31;
  float s = 0.f;
  for (int b = tid >> 5; b < 256; b += 8) s += p.gpart[b * 32 + c];
  red[tid] = s;
  __syncthreads();
  size_t base = (size_t)p.N * 32;
  if (tid < 32) {
    float t = 0.f;
#pragma unroll
    for (int i = 0; i < 8; ++i) t += red[i * 32 + tid];
    t /= (float)p.N;
    z[tid] = t;
    p.out[base + tid] = t;
  }
  __syncthreads();
  if (tid < 16) {
    float a = p.eb1[tid], b = p.mb1[tid];
    for (int k = 0; k < 32; ++k) {
      a += z[k] * p.eW1[k * 16 + tid];
      b += z[k] * p.mW1[k * 16 + tid];
    }
    hid[tid] = fmaxf(a, 0.f);
    hid[16 + tid] = fmaxf(b, 0.f);
  }
  __syncthreads();
  if (tid == 0) {
    float a = p.eb2[0];
    for (int k = 0; k < 16; ++k) a += hid[k] * p.eW2[k];
    p.out[base + 32] = 1.f / (1.f + __expf(-a));
  } else if (tid == 1) {
    float a = p.mb2[0];
    for (int k = 0; k < 16; ++k) a += hid[16 + k] * p.mW2[k];
    p.out[base + 33] = 1.f / (1.f + __expf(-a));
  }
}

// ==================== launch ====================
extern "C" void kernel_launch(void* const* d_in, const int* in_sizes, int n_in,
                              void* d_out, int out_size, void* d_ws, size_t ws_size,
                              hipStream_t stream) {
  const int N = in_sizes[0] / 5;
  const int E = in_sizes[1] / 2;
  const int M = E + N;

  Pr p;
  p.x = (const float*)d_in[0];
  const int* ei = (const int*)d_in[1];
  p.esrc = ei;
  p.edst = ei + E;
  p.encW = (const float*)d_in[2];
  p.encb = (const float*)d_in[3];
  for (int l = 0; l < 3; ++l) {
    const int o = 4 + 8 * l;
    p.W[l]  = (const float*)d_in[o + 0];
    p.as_[l] = (const float*)d_in[o + 1];
    p.ad[l] = (const float*)d_in[o + 2];
    p.b[l]  = (const float*)d_in[o + 3];
    p.g[l]  = (const float*)d_in[o + 4];
    p.be[l] = (const float*)d_in[o + 5];
    p.m[l]  = (const float*)d_in[o + 6];
    p.v[l]  = (const float*)d_in[o + 7];
  }
  p.eW1 = (const float*)d_in[28]; p.eb1 = (const float*)d_in[29];
  p.eW2 = (const float*)d_in[30]; p.eb2 = (const float*)d_in[31];
  p.mW1 = (const float*)d_in[32]; p.mb1 = (const float*)d_in[33];
  p.mW2 = (const float*)d_in[34]; p.mb2 = (const float*)d_in[35];
  p.out = (float*)d_out;
  p.N = N; p.E = E;

  float* wf = (float*)d_ws;
  size_t off = 0;
  p.hA = wf + off; off += (size_t)N * 64;
  p.hB = wf + off; off += (size_t)N * 64;
  p.xpb = (unsigned short*)(wf + off); off += (size_t)N * 128;  // N*256 bf16
  p.als = wf + off; off += (size_t)N * 4;
  p.ald = wf + off; off += (size_t)N * 4;
  p.pas = wf + off; off += 3 * 256;
  p.pad = wf + off; off += 3 * 256;
  int* wi = (int*)(wf + off);
  p.col = wi;                       // M
  p.rbeg = wi + M;                  // N
  p.rend = p.rbeg + N;              // N
  p.cursor = p.rend + N;            // N   } cursor, counter, gpart contiguous
  p.counter = p.cursor + N;         // 1   } (zeroed together in S0 / memset)
  p.gpart = (float*)(p.counter + 1);// 256*32

  // ---- try cooperative mega-kernel (occupancy-sized, checked) ----
  hipError_t st = hipErrorUnknown;
  int maxB = 0;
  if (hipOccupancyMaxActiveBlocksPerMultiprocessor(&maxB, (const void*)mega, TB, 0)
      != hipSuccess) maxB = 0;
  if (maxB > 4) maxB = 4;
  int gb = maxB * 256;  // 256 CUs on MI355X
  if (gb >= 256) {
    void* args[] = {&p};
    st = hipLaunchCooperativeKernel((const void*)mega, dim3(gb), dim3(TB), args, 0, stream);
  }
  if (st == hipSuccess) return;

  // ---- fallback: R7 multi-kernel path ----
  const int T = 256;
  const int gE = (E + T - 1) / T;
  const int gN = (N + T - 1) / T;
  const int gGE = (N + 15) / 16;

  hipMemsetAsync(p.cursor, 0, (size_t)(N + 1) * sizeof(int) + 256 * 32 * sizeof(float), stream);
  k_count<<<gE, T, 0, stream>>>(p.edst, p.cursor, E);
  k_alloc<<<gN, T, 0, stream>>>(p);
  k_scatter<<<gE, T, 0, stream>>>(p.esrc, p.edst, p.cursor, p.col, E);

  k_gemm_al<256, true><<<gGE, 256, 0, stream>>>(p, p.x, p.W[0], p.pas, p.pad);
  k_gather<64, true, false><<<(N + 3) / 4, 256, 0, stream>>>(p, p.hB, p.b[0], p.g[0],
                                                             p.be[0], p.m[0], p.v[0]);
  k_gemm_al<256, false><<<gGE, 256, 0, stream>>>(p, p.hB, p.W[1], p.pas + 256, p.pad + 256);
  k_gather<64, true, false><<<(N + 3) / 4, 256, 0, stream>>>(p, p.hA, p.b[1], p.g[1],
                                                             p.be[1], p.m[1], p.v[1]);
  k_gemm_al<128, false><<<gGE, 128, 0, stream>>>(p, p.hA, p.W[2], p.pas + 512, p.pad + 512);
  k_gather<32, false, true><<<(N + 3) / 4, 256, 0, stream>>>(p, p.out, p.b[2], p.g[2],
                                                             p.be[2], p.m[2], p.v[2]);
  k_heads2<<<1, 256, 0, stream>>>(p);
}